// Round 1
// baseline (1338.717 us; speedup 1.0000x reference)
//
#include <hip/hip_runtime.h>

#define NROWS 32768
#define DIM   512
#define HEADS 8
#define HDIM  64
#define LN_EPS 1e-5f

// ---------------------------------------------------------------------------
// GEMM: C[M,512] = A[M,512] @ B[512,512], optional relu epilogue.
// Block tile 64x64, BK=16, 256 threads, 4x4 micro-tile per thread.
// LDS rows padded to 68 floats (272 B = 17*16 B, keeps float4 alignment;
// resulting 2-way bank aliasing is free on gfx950 [m136]).
// ---------------------------------------------------------------------------
__global__ __launch_bounds__(256) void gemm_kernel(
    const float* __restrict__ A, const float* __restrict__ B,
    float* __restrict__ C, int relu)
{
    __shared__ float As[16][68];   // transposed: As[k][m]
    __shared__ float Bs[16][68];   // Bs[k][n]

    const int t  = threadIdx.x;
    const int bm = blockIdx.y * 64;
    const int bn = blockIdx.x * 64;
    const int tx = t & 15;         // 0..15  -> col quad
    const int ty = t >> 4;         // 0..15  -> row quad

    // staging-load indices
    const int am  = t >> 2;        // 0..63 : A-tile row
    const int ak  = (t & 3) * 4;   // 0,4,8,12 : A-tile k quad
    const int bk  = t >> 4;        // 0..15 : B-tile k row
    const int bn4 = (t & 15) * 4;  // 0..60 : B-tile col quad

    float acc[4][4] = {};

    for (int k0 = 0; k0 < DIM; k0 += 16) {
        const float4 av = *(const float4*)(A + (size_t)(bm + am) * DIM + k0 + ak);
        As[ak + 0][am] = av.x;
        As[ak + 1][am] = av.y;
        As[ak + 2][am] = av.z;
        As[ak + 3][am] = av.w;
        *(float4*)&Bs[bk][bn4] =
            *(const float4*)(B + (size_t)(k0 + bk) * DIM + bn + bn4);
        __syncthreads();

        #pragma unroll
        for (int kk = 0; kk < 16; ++kk) {
            const float4 a = *(const float4*)&As[kk][ty * 4];
            const float4 b = *(const float4*)&Bs[kk][tx * 4];
            const float ar[4] = {a.x, a.y, a.z, a.w};
            const float br[4] = {b.x, b.y, b.z, b.w};
            #pragma unroll
            for (int i = 0; i < 4; ++i)
                #pragma unroll
                for (int j = 0; j < 4; ++j)
                    acc[i][j] += ar[i] * br[j];
        }
        __syncthreads();
    }

    #pragma unroll
    for (int i = 0; i < 4; ++i) {
        float4 o = make_float4(acc[i][0], acc[i][1], acc[i][2], acc[i][3]);
        if (relu) {
            o.x = fmaxf(o.x, 0.f); o.y = fmaxf(o.y, 0.f);
            o.z = fmaxf(o.z, 0.f); o.w = fmaxf(o.w, 0.f);
        }
        *(float4*)(C + (size_t)(bm + ty * 4 + i) * DIM + bn + tx * 4) = o;
    }
}

// ---------------------------------------------------------------------------
// Per-row linear attention: one block (256 thr) per row b.
//   kv[d][e]  = sum_h k[h,d] * v[h,e]        (64x64)
//   ksum[d]   = sum_h k[h,d]
//   num[n,e]  = sum_d q[n,d] * kv[d][e]
//   denom[n]  = sum_d q[n,d] * ksum[d]
//   attn[n,e] = num / denom
// ---------------------------------------------------------------------------
__global__ __launch_bounds__(256) void attn_kernel(
    const float* __restrict__ q, const float* __restrict__ k,
    const float* __restrict__ v, float* __restrict__ attn)
{
    __shared__ float sq[DIM], sk[DIM], sv[DIM];
    __shared__ float skv[64][65];
    __shared__ float sksum[64];
    __shared__ float sden[HEADS];

    const int t = threadIdx.x;
    const size_t base = (size_t)blockIdx.x * DIM;

    for (int i = t; i < DIM; i += 256) {
        sq[i] = q[base + i];
        sk[i] = k[base + i];
        sv[i] = v[base + i];
    }
    __syncthreads();

    // kv outer-product accumulation: thread -> (d, 16 consecutive e)
    {
        const int d  = t >> 2;          // 0..63
        const int e0 = (t & 3) * 16;    // 0,16,32,48
        float acc[16] = {};
        #pragma unroll
        for (int h = 0; h < HEADS; ++h) {
            const float kd = sk[h * 64 + d];
            #pragma unroll
            for (int j = 0; j < 16; ++j)
                acc[j] += kd * sv[h * 64 + e0 + j];
        }
        #pragma unroll
        for (int j = 0; j < 16; ++j) skv[d][e0 + j] = acc[j];
    }
    if (t < 64) {
        float s = 0.f;
        #pragma unroll
        for (int h = 0; h < HEADS; ++h) s += sk[h * 64 + t];
        sksum[t] = s;
    }
    __syncthreads();

    if (t < HEADS) {
        float s = 0.f;
        #pragma unroll
        for (int d = 0; d < 64; ++d) s += sq[t * 64 + d] * sksum[d];
        sden[t] = s;
    }
    __syncthreads();

    for (int idx = t; idx < DIM; idx += 256) {
        const int n = idx >> 6;
        const int e = idx & 63;
        float s = 0.f;
        #pragma unroll
        for (int d = 0; d < 64; ++d) s += sq[n * 64 + d] * skv[d][e];
        attn[base + idx] = s / sden[n];
    }
}

// ---------------------------------------------------------------------------
// LayerNorm(h + fh) * gamma + beta — one wave (64 lanes) per row, 4 rows/block.
// ---------------------------------------------------------------------------
__global__ __launch_bounds__(256) void ln_kernel(
    const float* __restrict__ h, const float* __restrict__ fh,
    const float* __restrict__ gamma, const float* __restrict__ beta,
    float* __restrict__ out)
{
    const int lane = threadIdx.x & 63;
    const int wave = threadIdx.x >> 6;
    const size_t base = ((size_t)blockIdx.x * 4 + wave) * DIM;

    float x[8];
    float s = 0.f;
    #pragma unroll
    for (int i = 0; i < 8; ++i) {
        const int j = lane + i * 64;
        x[i] = h[base + j] + fh[base + j];
        s += x[i];
    }
    #pragma unroll
    for (int off = 32; off > 0; off >>= 1) s += __shfl_down(s, off);
    const float mu = __shfl(s, 0) * (1.f / DIM);

    float vs = 0.f;
    #pragma unroll
    for (int i = 0; i < 8; ++i) {
        const float d = x[i] - mu;
        vs += d * d;
    }
    #pragma unroll
    for (int off = 32; off > 0; off >>= 1) vs += __shfl_down(vs, off);
    const float rstd = rsqrtf(__shfl(vs, 0) * (1.f / DIM) + LN_EPS);

    #pragma unroll
    for (int i = 0; i < 8; ++i) {
        const int j = lane + i * 64;
        out[base + j] = (x[i] - mu) * rstd * gamma[j] + beta[j];
    }
}

// ---------------------------------------------------------------------------
extern "C" void kernel_launch(void* const* d_in, const int* in_sizes, int n_in,
                              void* d_out, int out_size, void* d_ws, size_t ws_size,
                              hipStream_t stream)
{
    const float* h     = (const float*)d_in[0];
    const float* Wq    = (const float*)d_in[1];
    const float* Wk    = (const float*)d_in[2];
    const float* Wv    = (const float*)d_in[3];
    const float* Wf    = (const float*)d_in[4];
    const float* gamma = (const float*)d_in[5];
    const float* beta  = (const float*)d_in[6];

    const size_t ND = (size_t)NROWS * DIM;
    float* out  = (float*)d_out;       // final LN output  [0, ND)
    float* qo   = out + ND;            // q output
    float* ko   = out + 2 * ND;        // k output
    float* vo   = out + 3 * ND;        // v output
    float* attn = out;                 // stage attn in out-region (dead until LN)
    float* fh   = (float*)d_ws;        // ND floats of scratch

    const dim3 gemm_grid(DIM / 64, NROWS / 64);   // (8, 512)

    gemm_kernel<<<gemm_grid, 256, 0, stream>>>(h, Wq, qo, 1);
    gemm_kernel<<<gemm_grid, 256, 0, stream>>>(h, Wk, ko, 1);
    gemm_kernel<<<gemm_grid, 256, 0, stream>>>(h, Wv, vo, 0);
    attn_kernel<<<NROWS, 256, 0, stream>>>(qo, ko, vo, attn);
    gemm_kernel<<<gemm_grid, 256, 0, stream>>>(attn, Wf, fh, 0);
    ln_kernel<<<NROWS / 4, 256, 0, stream>>>(h, fh, gamma, beta, out);
}

// Round 2
// 543.117 us; speedup vs baseline: 2.4649x; 2.4649x over previous
//
#include <hip/hip_runtime.h>
#include <hip/hip_bf16.h>

#define NROWS 32768
#define DIM   512
#define HEADS 8
#define LN_EPS 1e-5f

typedef __attribute__((ext_vector_type(8))) short short8;   // 8 bf16 (4 VGPRs)
typedef __attribute__((ext_vector_type(4))) float floatx4;  // MFMA acc

typedef __attribute__((address_space(3))) void lds_void;
typedef __attribute__((address_space(1))) void gbl_void;

// async global->LDS, 16 B per lane; LDS dest = wave-uniform base + lane*16
__device__ __forceinline__ void async16(const void* g, void* l) {
    __builtin_amdgcn_global_load_lds(
        (gbl_void*)(unsigned long long)(uintptr_t)g,
        (lds_void*)(unsigned int)(uintptr_t)l,
        16, 0, 0);
}

// ---------------------------------------------------------------------------
// h (fp32) -> hb (bf16), vectorized
// ---------------------------------------------------------------------------
__global__ __launch_bounds__(256) void hconv_kernel(
    const float* __restrict__ h, __hip_bfloat16* __restrict__ hb)
{
    const size_t i = ((size_t)blockIdx.x * 256 + threadIdx.x) * 4;
    const float4 f = *(const float4*)(h + i);
    union { ushort4 u; __hip_bfloat16 b[4]; } pk;
    pk.b[0] = __float2bfloat16(f.x);
    pk.b[1] = __float2bfloat16(f.y);
    pk.b[2] = __float2bfloat16(f.z);
    pk.b[3] = __float2bfloat16(f.w);
    *(ushort4*)(hb + i) = pk.u;
}

// ---------------------------------------------------------------------------
// W [K=512][N=512] fp32 -> Wt [N][K] bf16 (transpose + convert), 32x32 tiles
// ---------------------------------------------------------------------------
__global__ __launch_bounds__(256) void wtrans_kernel(
    const float* __restrict__ W, __hip_bfloat16* __restrict__ Wt)
{
    __shared__ float tile[32][33];
    const int bn = blockIdx.x * 32;   // n block
    const int bk = blockIdx.y * 32;   // k block
    const int tx = threadIdx.x & 31;
    const int ty = threadIdx.x >> 5;  // 0..7
    #pragma unroll
    for (int i = ty; i < 32; i += 8)
        tile[i][tx] = W[(size_t)(bk + i) * DIM + bn + tx];
    __syncthreads();
    #pragma unroll
    for (int i = ty; i < 32; i += 8)
        Wt[(size_t)(bn + i) * DIM + bk + tx] = __float2bfloat16(tile[tx][i]);
}

// ---------------------------------------------------------------------------
// MFMA GEMM: C[M,512] fp32 = A[M,512](bf16) @ Bt[n][k](bf16)^T, opt relu.
// 128x128 tile, BK=32, 256 thr = 4 waves (2x2), 4x4 16x16x32 frags per wave.
// LDS layout: 16B chunks, chunk = row*4 + (kq ^ ((row>>1)&3))  (XOR swizzle
// -> frag ds_read_b128 is 2-way per bank group = free [m136]).
// Staged via global_load_lds width=16 (lane's gptr chosen to realize swizzle).
// ---------------------------------------------------------------------------
__global__ __launch_bounds__(256) void mfma_gemm_kernel(
    const __hip_bfloat16* __restrict__ A,
    const __hip_bfloat16* __restrict__ Bt,
    float* __restrict__ C, int relu)
{
    __shared__ __align__(16) char smem[16384];   // As 8 KB | Bs 8 KB

    const int t    = threadIdx.x;
    const int lane = t & 63;
    const int w    = t >> 6;
    const int wm   = w >> 1, wn = w & 1;
    const int l16  = lane & 15, quad = lane >> 4;
    const int bm   = blockIdx.y * 128;
    const int bn   = blockIdx.x * 128;

    // staging: 512 chunks per tile; wave w covers chunks [w*128, w*128+128)
    const int c0 = w * 128 + lane;
    const int c1 = c0 + 64;
    const int r0 = c0 >> 2, kq0 = (c0 & 3) ^ ((r0 >> 1) & 3);
    const int r1 = c1 >> 2, kq1 = (c1 & 3) ^ ((r1 >> 1) & 3);

    const __hip_bfloat16* gA0 = A  + (size_t)(bm + r0) * DIM + kq0 * 8;
    const __hip_bfloat16* gA1 = A  + (size_t)(bm + r1) * DIM + kq1 * 8;
    const __hip_bfloat16* gB0 = Bt + (size_t)(bn + r0) * DIM + kq0 * 8;
    const __hip_bfloat16* gB1 = Bt + (size_t)(bn + r1) * DIM + kq1 * 8;

    char* dA0 = smem + (w * 128 +  0) * 16;        // wave-uniform LDS bases
    char* dA1 = smem + (w * 128 + 64) * 16;
    char* dB0 = smem + 8192 + (w * 128 +  0) * 16;
    char* dB1 = smem + 8192 + (w * 128 + 64) * 16;

    // loop-invariant frag LDS byte offsets
    int aoff[4], boff[4];
    #pragma unroll
    for (int i = 0; i < 4; ++i) {
        const int ra = wm * 64 + i * 16 + l16;
        aoff[i] = (ra * 4 + (quad ^ ((ra >> 1) & 3))) * 16;
        const int rb = wn * 64 + i * 16 + l16;
        boff[i] = 8192 + (rb * 4 + (quad ^ ((rb >> 1) & 3))) * 16;
    }

    floatx4 acc[4][4];
    #pragma unroll
    for (int i = 0; i < 4; ++i)
        #pragma unroll
        for (int j = 0; j < 4; ++j)
            acc[i][j] = (floatx4){0.f, 0.f, 0.f, 0.f};

    for (int k0 = 0; k0 < DIM; k0 += 32) {
        async16(gA0 + k0, dA0);
        async16(gA1 + k0, dA1);
        async16(gB0 + k0, dB0);
        async16(gB1 + k0, dB1);
        __syncthreads();   // drains vmcnt incl. global_load_lds

        short8 af[4], bf[4];
        #pragma unroll
        for (int i = 0; i < 4; ++i) af[i] = *(const short8*)(smem + aoff[i]);
        #pragma unroll
        for (int j = 0; j < 4; ++j) bf[j] = *(const short8*)(smem + boff[j]);

        #pragma unroll
        for (int i = 0; i < 4; ++i)
            #pragma unroll
            for (int j = 0; j < 4; ++j)
                acc[i][j] = __builtin_amdgcn_mfma_f32_16x16x32_bf16(
                    af[i], bf[j], acc[i][j], 0, 0, 0);

        __syncthreads();   // LDS reuse next iter
    }

    // epilogue: D row = quad*4 + reg, col = lane&15  [m89]
    #pragma unroll
    for (int i = 0; i < 4; ++i) {
        const int gr = bm + wm * 64 + i * 16 + quad * 4;
        #pragma unroll
        for (int j = 0; j < 4; ++j) {
            const int gc = bn + wn * 64 + j * 16 + l16;
            #pragma unroll
            for (int rg = 0; rg < 4; ++rg) {
                float vv = acc[i][j][rg];
                if (relu) vv = fmaxf(vv, 0.f);
                C[(size_t)(gr + rg) * DIM + gc] = vv;
            }
        }
    }
}

// ---------------------------------------------------------------------------
// Linear attention, 2 rows per block (128 thr each), float4 LDS paths.
// Writes attn directly as bf16 (input to the Wf GEMM).
// ---------------------------------------------------------------------------
__global__ __launch_bounds__(256) void attn_kernel(
    const float* __restrict__ q, const float* __restrict__ k,
    const float* __restrict__ v, __hip_bfloat16* __restrict__ attn)
{
    __shared__ float sq[2][DIM], sk[2][DIM], sv[2][DIM];
    __shared__ float skv[2][64][68];
    __shared__ float sksum[2][64];

    const int t = threadIdx.x;
    const int r = t >> 7;          // row half 0/1
    const int u = t & 127;
    const size_t base = ((size_t)blockIdx.x * 2 + r) * DIM;

    ((float4*)sq[r])[u] = ((const float4*)(q + base))[u];
    ((float4*)sk[r])[u] = ((const float4*)(k + base))[u];
    ((float4*)sv[r])[u] = ((const float4*)(v + base))[u];
    __syncthreads();

    const int e0 = (u & 15) * 4;   // e quad
    const int d0 = (u >> 4) * 8;   // 8 d values (kv phase)

    if (u < 64) {                  // ksum[d] = sum_h k[h,d]
        float s = 0.f;
        #pragma unroll
        for (int h = 0; h < HEADS; ++h) s += sk[r][h * 64 + u];
        sksum[r][u] = s;
    }

    // kv[d][e] = sum_h k[h,d] v[h,e] : thread -> 8 d x 4 e
    float4 acc[8];
    #pragma unroll
    for (int i = 0; i < 8; ++i) acc[i] = make_float4(0.f, 0.f, 0.f, 0.f);
    #pragma unroll
    for (int h = 0; h < HEADS; ++h) {
        const float4 v4 = *(const float4*)&sv[r][h * 64 + e0];
        #pragma unroll
        for (int i = 0; i < 8; ++i) {
            const float kd = sk[r][h * 64 + d0 + i];
            acc[i].x += kd * v4.x; acc[i].y += kd * v4.y;
            acc[i].z += kd * v4.z; acc[i].w += kd * v4.w;
        }
    }
    #pragma unroll
    for (int i = 0; i < 8; ++i)
        *(float4*)&skv[r][d0 + i][e0] = acc[i];
    __syncthreads();

    // num + denom: thread -> head n = u>>4, e quad e0
    const int n = u >> 4;
    float sx = 0.f, sy = 0.f, sz = 0.f, sw = 0.f, den = 0.f;
    #pragma unroll 8
    for (int d = 0; d < 64; ++d) {
        const float qd = sq[r][n * 64 + d];
        const float4 kv4 = *(const float4*)&skv[r][d][e0];
        sx += qd * kv4.x; sy += qd * kv4.y;
        sz += qd * kv4.z; sw += qd * kv4.w;
        den += qd * sksum[r][d];
    }
    union { ushort4 us; __hip_bfloat16 b[4]; } pk;
    pk.b[0] = __float2bfloat16(sx / den);
    pk.b[1] = __float2bfloat16(sy / den);
    pk.b[2] = __float2bfloat16(sz / den);
    pk.b[3] = __float2bfloat16(sw / den);
    *(ushort4*)(attn + base + n * 64 + e0) = pk.us;
}

// ---------------------------------------------------------------------------
// LayerNorm(h + fh)*gamma + beta — one wave per row, 4 rows/block.
// NOTE: fh may alias out (same-address read-then-write per thread) — no
// __restrict__ on those two.
// ---------------------------------------------------------------------------
__global__ __launch_bounds__(256) void ln_kernel(
    const float* __restrict__ h, const float* fh,
    const float* __restrict__ gamma, const float* __restrict__ beta,
    float* out)
{
    const int lane = threadIdx.x & 63;
    const int wave = threadIdx.x >> 6;
    const size_t base = ((size_t)blockIdx.x * 4 + wave) * DIM;

    float x[8];
    float s = 0.f;
    #pragma unroll
    for (int i = 0; i < 8; ++i) {
        const int j = lane + i * 64;
        x[i] = h[base + j] + fh[base + j];
        s += x[i];
    }
    #pragma unroll
    for (int off = 32; off > 0; off >>= 1) s += __shfl_down(s, off);
    const float mu = __shfl(s, 0) * (1.f / DIM);

    float vs = 0.f;
    #pragma unroll
    for (int i = 0; i < 8; ++i) { const float d = x[i] - mu; vs += d * d; }
    #pragma unroll
    for (int off = 32; off > 0; off >>= 1) vs += __shfl_down(vs, off);
    const float rstd = rsqrtf(__shfl(vs, 0) * (1.f / DIM) + LN_EPS);

    #pragma unroll
    for (int i = 0; i < 8; ++i) {
        const int j = lane + i * 64;
        out[base + j] = (x[i] - mu) * rstd * gamma[j] + beta[j];
    }
}

// ---------------------------------------------------------------------------
extern "C" void kernel_launch(void* const* d_in, const int* in_sizes, int n_in,
                              void* d_out, int out_size, void* d_ws, size_t ws_size,
                              hipStream_t stream)
{
    const float* h     = (const float*)d_in[0];
    const float* Wq    = (const float*)d_in[1];
    const float* Wk    = (const float*)d_in[2];
    const float* Wv    = (const float*)d_in[3];
    const float* Wf    = (const float*)d_in[4];
    const float* gamma = (const float*)d_in[5];
    const float* beta  = (const float*)d_in[6];

    const size_t ND = (size_t)NROWS * DIM;
    float* out = (float*)d_out;
    float* qo  = out + ND;
    float* ko  = out + 2 * ND;
    float* vo  = out + 3 * ND;
    float* fh  = out;                       // stage fh in out[0..ND) (dead until LN)

    __hip_bfloat16* hb  = (__hip_bfloat16*)d_ws;     // ND bf16 (32 MB)
    __hip_bfloat16* wtq = hb + ND;                   // 4 x 512x512 bf16 (2 MB)
    __hip_bfloat16* wtk = wtq + DIM * DIM;
    __hip_bfloat16* wtv = wtk + DIM * DIM;
    __hip_bfloat16* wtf = wtv + DIM * DIM;
    __hip_bfloat16* attnb = hb;                      // reuse hb region (dead after v GEMM)

    const dim3 ggrid(DIM / 128, NROWS / 128);        // (4, 256)
    const dim3 wgrid(16, 16);

    hconv_kernel<<<NROWS * DIM / 1024, 256, 0, stream>>>(h, hb);
    wtrans_kernel<<<wgrid, 256, 0, stream>>>(Wq, wtq);
    wtrans_kernel<<<wgrid, 256, 0, stream>>>(Wk, wtk);
    wtrans_kernel<<<wgrid, 256, 0, stream>>>(Wv, wtv);
    wtrans_kernel<<<wgrid, 256, 0, stream>>>(Wf, wtf);

    mfma_gemm_kernel<<<ggrid, 256, 0, stream>>>(hb, wtq, qo, 1);
    mfma_gemm_kernel<<<ggrid, 256, 0, stream>>>(hb, wtk, ko, 1);
    mfma_gemm_kernel<<<ggrid, 256, 0, stream>>>(hb, wtv, vo, 0);

    attn_kernel<<<NROWS / 2, 256, 0, stream>>>(qo, ko, vo, attnb);

    mfma_gemm_kernel<<<ggrid, 256, 0, stream>>>(attnb, wtf, fh, 0);

    ln_kernel<<<NROWS / 4, 256, 0, stream>>>(h, fh, gamma, beta, out);
}